// Round 4
// baseline (1092.011 us; speedup 1.0000x reference)
//
#include <hip/hip_runtime.h>
#include <cstdint>
#include <cstddef>

// ============================================================================
// new_clsnet on MI355X — round 8: kill gemm_h's fp32-cvt critical path.
// r7 counters (gemm_h 143us): MfmaUtil 42.5%, VALUBusy 27.4%, HBM 16%,
// Occ 22%, conflicts 8.4e6 -> VALU = in-loop fp32->bf16 cvt (frag_f) on the
// ds_read->MFMA path; A staged fp32 (2x bytes, 64K LDS, 2 blk/CU).
// Fixes:
//  (a) gemm_h A -> featH (pre-converted bf16; s11 proves this path is clean).
//      48K LDS -> 3 blk/CU, no cvt VALU, half the A-stage instrs. H written
//      IN-PLACE over Z0 (read-then-write same address, bijective) since
//      featH's region must stay live as the A operand.
//  (b) GT = G^T via 8MiB bf16 transpose instead of a second 2048^3 GEMM.
//  (c) merge feat_norm+cvt(feat) -> featcvt_k, emb_norm+cvt(emb) -> embcvt_k
//      (single read of feat/emb instead of two).
// Memory map:
//   ws[1,9) G | ws[9,17) GT -> embH/embL | ws[17,25) M1 -> fc_wB | ws[25,33) M2
//   oq[0,24) KwT/QwT/VwT, oq[24,40) fuse_wB (dead after big4)
//   then oq[0,32MiB) featH (live..gemm_h) | oq[32,64) featL -> Z0 -> H(inplace)
//   out_pred = EG|EGT|T1|T2 (exact fit) until pred overwrites.
// ============================================================================

typedef __bf16 bf16;
typedef __bf16 bf16x8 __attribute__((ext_vector_type(8)));
typedef float  f32x4  __attribute__((ext_vector_type(4)));

#define TO_AS1(p) ((__attribute__((address_space(1))) void*)(uintptr_t)(p))
#define TO_AS3(p) ((__attribute__((address_space(3))) void*)(uintptr_t)(p))

enum { EPI_DIST = 1, EPI_SCORES = 2, EPI_BIAS = 4 };

// ---- staging: 128x64-elem tile, linear LDS dest, XOR-swizzled global src ---
// LDS position chunk p (16B) holds source chunk (p%CPR)^(rloc&7) of row rloc.
__device__ __forceinline__ void stage_b(const bf16* __restrict__ src, char* lds,
                                        int rbase, int ld, int k0, int clamp,
                                        int tid) {
  const int wb = tid & ~63, lane = tid & 63;
#pragma unroll
  for (int it = 0; it < 4; ++it) {
    const int chunk = it * 256 + wb + lane;
    const int rloc = chunk >> 3;  // 8 chunks per 64-elem bf16 row
    int row = rbase + rloc;
    if (row > clamp) row = clamp;
    const int sc = (chunk & 7) ^ (rloc & 7);
    const bf16* gp = src + (size_t)row * ld + k0 + sc * 8;
    __builtin_amdgcn_global_load_lds(TO_AS1(gp),
                                     TO_AS3(lds + (it * 256 + wb) * 16), 16, 0,
                                     0);
  }
}

__device__ __forceinline__ void stage_f(const float* __restrict__ src,
                                        char* lds, int rbase, int ld, int k0,
                                        int clamp, int tid) {
  const int wb = tid & ~63, lane = tid & 63;
#pragma unroll
  for (int it = 0; it < 8; ++it) {
    const int chunk = it * 256 + wb + lane;
    const int rloc = chunk >> 4;  // 16 chunks per 64-elem fp32 row
    int row = rbase + rloc;
    if (row > clamp) row = clamp;
    const int sc = (chunk & 15) ^ (rloc & 7);
    const float* gp = src + (size_t)row * ld + k0 + sc * 4;
    __builtin_amdgcn_global_load_lds(TO_AS1(gp),
                                     TO_AS3(lds + (it * 256 + wb) * 16), 16, 0,
                                     0);
  }
}

// ---- fragment loads (apply the same XOR on the read address) --------------
__device__ __forceinline__ bf16x8 frag_b(const char* lds, int r, int koff) {
  const int cc = (koff >> 3) ^ (r & 7);
  return *(const bf16x8*)(lds + r * 128 + cc * 16);
}

__device__ __forceinline__ bf16x8 frag_f(const char* lds, int r, int koff) {
  const int c0 = koff >> 2;  // even
  const f32x4 v0 = *(const f32x4*)(lds + r * 256 + ((c0 ^ (r & 7)) << 4));
  const f32x4 v1 =
      *(const f32x4*)(lds + r * 256 + (((c0 + 1) ^ (r & 7)) << 4));
  bf16x8 h;
#pragma unroll
  for (int t = 0; t < 4; ++t) { h[t] = (bf16)v0[t]; h[4 + t] = (bf16)v1[t]; }
  return h;
}

// ---------------------------------------------------------------------------
// C[m,n] = sum_k A[m,k]*B[n,k]; 128x128 tile, BK=64, 256 thr, mfma 16x16x32.
// All operands bf16 (pre-converted). TRIPLE: A/B given as hi+lo pairs,
// acc += AH*BH + AH*BL + AL*BH (fp32-grade for argmin).
// ---------------------------------------------------------------------------
template <int EPI, bool TRIPLE, int MINW>
__global__ __launch_bounds__(256, MINW) void gemm_nt(
    const bf16* __restrict__ AH, const bf16* __restrict__ AL,
    const bf16* __restrict__ BH, const bf16* __restrict__ BL,
    void* __restrict__ Cout, const float* __restrict__ bias,
    const float* __restrict__ qp, float* __restrict__ sA,
    const float* __restrict__ nx, const float* __restrict__ nw,
    const float* __restrict__ sw, float* __restrict__ Dmin,
    int* __restrict__ Darg, int K, int lda, int ldb, int ldc, int nclamp) {
  __shared__ __align__(16) char AsH[16384];
  __shared__ __align__(16) char BsH[16384];
  __shared__ __align__(16) char AsL[TRIPLE ? 16384 : 16];
  __shared__ __align__(16) char BsL[TRIPLE ? 16384 : 16];

  const int tid = threadIdx.x;
  const int wave = tid >> 6, lane = tid & 63;
  const int bm = blockIdx.x * 128, bn = blockIdx.y * 128;

  f32x4 acc[4][4] = {};

  const int fm = lane & 15;
  const int fk = (lane >> 4) * 8;
  const int wm = (wave >> 1) * 64;
  const int wn = (wave & 1) * 64;

  for (int k0 = 0; k0 < K; k0 += 64) {
    stage_b(AH, AsH, bm, lda, k0, 1 << 30, tid);
    stage_b(BH, BsH, bn, ldb, k0, nclamp, tid);
    if constexpr (TRIPLE) {
      stage_b(AL, AsL, bm, lda, k0, 1 << 30, tid);
      stage_b(BL, BsL, bn, ldb, k0, nclamp, tid);
    }
    __builtin_amdgcn_s_waitcnt(0);
    __syncthreads();
#pragma unroll
    for (int ks = 0; ks < 2; ++ks) {
      const int ko = ks * 32 + fk;
      bf16x8 ah[4], bh[4];
#pragma unroll
      for (int i = 0; i < 4; ++i) ah[i] = frag_b(AsH, wm + 16 * i + fm, ko);
#pragma unroll
      for (int j = 0; j < 4; ++j) bh[j] = frag_b(BsH, wn + 16 * j + fm, ko);
      if constexpr (TRIPLE) {
        bf16x8 al[4], bl[4];
#pragma unroll
        for (int i = 0; i < 4; ++i) al[i] = frag_b(AsL, wm + 16 * i + fm, ko);
#pragma unroll
        for (int j = 0; j < 4; ++j) bl[j] = frag_b(BsL, wn + 16 * j + fm, ko);
#pragma unroll
        for (int i = 0; i < 4; ++i)
#pragma unroll
          for (int j = 0; j < 4; ++j) {
            acc[i][j] = __builtin_amdgcn_mfma_f32_16x16x32_bf16(
                ah[i], bh[j], acc[i][j], 0, 0, 0);
            acc[i][j] = __builtin_amdgcn_mfma_f32_16x16x32_bf16(
                ah[i], bl[j], acc[i][j], 0, 0, 0);
            acc[i][j] = __builtin_amdgcn_mfma_f32_16x16x32_bf16(
                al[i], bh[j], acc[i][j], 0, 0, 0);
          }
      } else {
#pragma unroll
        for (int i = 0; i < 4; ++i)
#pragma unroll
          for (int j = 0; j < 4; ++j)
            acc[i][j] = __builtin_amdgcn_mfma_f32_16x16x32_bf16(
                ah[i], bh[j], acc[i][j], 0, 0, 0);
      }
    }
    __syncthreads();
  }

  // epilogue; C/D layout: col=lane&15, row=(lane>>4)*4+r (m89-verified)
  const int r0 = (lane >> 4) * 4;

  if constexpr (EPI == EPI_DIST) {
    __shared__ float vred[256];
    __shared__ int ared[256];
    const float INF = 3.4e38f;
#pragma unroll
    for (int i = 0; i < 4; ++i) {
#pragma unroll
      for (int r = 0; r < 4; ++r) {
        const int rl = wm + 16 * i + r0 + r;
        const float rx = nx[bm + rl];
        float best = INF;
        int barg = 0;
#pragma unroll
        for (int j = 0; j < 4; ++j) {
          const int col = bn + wn + 16 * j + fm;
          if (col <= nclamp) {
            float s = sw[col] - 2.0f * acc[i][j][r] / (rx * nw[col]);
            if (s < best) { best = s; barg = col; }
          }
        }
#pragma unroll
        for (int o = 8; o >= 1; o >>= 1) {
          float ob = __shfl_xor(best, o, 64);
          int oa = __shfl_xor(barg, o, 64);
          if (ob < best || (ob == best && oa < barg)) { best = ob; barg = oa; }
        }
        if (fm == 0) {
          vred[rl * 2 + (wave & 1)] = best;
          ared[rl * 2 + (wave & 1)] = barg;
        }
      }
    }
    __syncthreads();
    if (tid < 128) {
      float v0 = vred[tid * 2], v1 = vred[tid * 2 + 1];
      int a0 = ared[tid * 2], a1 = ared[tid * 2 + 1];
      float bv = v0; int ba = a0;
      if (v1 < bv || (v1 == bv && a1 < ba)) { bv = v1; ba = a1; }
      Dmin[(size_t)(bm + tid) * 8 + blockIdx.y] = bv;
      Darg[(size_t)(bm + tid) * 8 + blockIdx.y] = ba;
    }
    return;
  }

  if constexpr (EPI == EPI_SCORES) {
#pragma unroll
    for (int i = 0; i < 4; ++i) {
#pragma unroll
      for (int r = 0; r < 4; ++r) {
        const int row = bm + wm + 16 * i + r0 + r;
        float pa = 0.f;
#pragma unroll
        for (int j = 0; j < 4; ++j) {
          const int col = bn + wn + 16 * j + fm;
          pa += qp[(size_t)row * 2048 + col] * acc[i][j][r];
        }
#pragma unroll
        for (int o = 8; o >= 1; o >>= 1) pa += __shfl_xor(pa, o, 64);
        if (fm == 0) atomicAdd(&sA[row], pa);
      }
    }
    return;
  }

  // EPI_BIAS: fp32 out, ragged-guarded cols
#pragma unroll
  for (int i = 0; i < 4; ++i)
#pragma unroll
    for (int j = 0; j < 4; ++j) {
      const int col = bn + wn + 16 * j + fm;
#pragma unroll
      for (int r = 0; r < 4; ++r) {
        const int row = bm + wm + 16 * i + r0 + r;
        int bc = col <= nclamp ? col : nclamp;
        float v = acc[i][j][r] + bias[bc];
        if (col <= nclamp) ((float*)Cout)[(size_t)row * ldc + col] = v;
      }
    }
}

// ---------------------------------------------------------------------------
// z-batched 4-GEMM. AF32: A operands fp32-staged (emb4); else bf16.
// lda: z==0 -> lda0, else ldaR.
// ---------------------------------------------------------------------------
template <bool AF32, bool F32OUT, int MINW>
__global__ __launch_bounds__(256, MINW) void gemm4_nt(
    const void* a0, const void* a1, const void* a2, const void* a3,
    const bf16* b0, const bf16* b1, const bf16* b2, const bf16* b3, void* c0,
    void* c1, void* c2, void* c3, int K, int lda0, int ldaR, int ldb,
    int ldc, int mclamp) {
  __shared__ __align__(16) char AsRaw[AF32 ? 32768 : 16384];
  __shared__ __align__(16) char BsRaw[16384];
  const int z = blockIdx.z;
  const void* A = z == 0 ? a0 : z == 1 ? a1 : z == 2 ? a2 : a3;
  const bf16* B = z == 0 ? b0 : z == 1 ? b1 : z == 2 ? b2 : b3;
  void* C = z == 0 ? c0 : z == 1 ? c1 : z == 2 ? c2 : c3;
  const int lda = (z == 0) ? lda0 : ldaR;

  const int tid = threadIdx.x;
  const int wave = tid >> 6, lane = tid & 63;
  const int bm = blockIdx.x * 128, bn = blockIdx.y * 128;
  f32x4 acc[4][4] = {};
  const int fm = lane & 15, fk = (lane >> 4) * 8;
  const int wm = (wave >> 1) * 64, wn = (wave & 1) * 64;

  for (int k0 = 0; k0 < K; k0 += 64) {
    if constexpr (AF32)
      stage_f((const float*)A, AsRaw, bm, lda, k0, mclamp, tid);
    else
      stage_b((const bf16*)A, AsRaw, bm, lda, k0, mclamp, tid);
    stage_b(B, BsRaw, bn, ldb, k0, 1 << 30, tid);
    __builtin_amdgcn_s_waitcnt(0);
    __syncthreads();
#pragma unroll
    for (int ks = 0; ks < 2; ++ks) {
      const int ko = ks * 32 + fk;
      bf16x8 ah[4], bh[4];
#pragma unroll
      for (int i = 0; i < 4; ++i)
        ah[i] = AF32 ? frag_f(AsRaw, wm + 16 * i + fm, ko)
                     : frag_b(AsRaw, wm + 16 * i + fm, ko);
#pragma unroll
      for (int j = 0; j < 4; ++j) bh[j] = frag_b(BsRaw, wn + 16 * j + fm, ko);
#pragma unroll
      for (int i = 0; i < 4; ++i)
#pragma unroll
        for (int j = 0; j < 4; ++j)
          acc[i][j] = __builtin_amdgcn_mfma_f32_16x16x32_bf16(ah[i], bh[j],
                                                              acc[i][j], 0, 0, 0);
    }
    __syncthreads();
  }

  const int r0 = (lane >> 4) * 4;
#pragma unroll
  for (int i = 0; i < 4; ++i)
#pragma unroll
    for (int j = 0; j < 4; ++j) {
      const int col = bn + wn + 16 * j + fm;
#pragma unroll
      for (int r = 0; r < 4; ++r) {
        const int row = bm + wm + 16 * i + r0 + r;
        if (row <= mclamp) {
          if constexpr (F32OUT)
            ((float*)C)[(size_t)row * ldc + col] = acc[i][j][r];
          else
            ((bf16*)C)[(size_t)row * ldc + col] = (bf16)acc[i][j][r];
        }
      }
    }
}

// ---------------------------------------------------------------------------
// dual-B h-GEMM: acc1=featH@M1^T, acc2=featH@M2^T (all-bf16), fused epilogue
// h = relu(a10*acc1 + a11*acc2 + Z0[row][col]); H written in-place over Z0.
// ---------------------------------------------------------------------------
__global__ __launch_bounds__(256, 3) void gemm_h(
    const bf16* __restrict__ A, const bf16* __restrict__ B1,
    const bf16* __restrict__ B2, bf16* __restrict__ H,
    const bf16* __restrict__ Z0, const float* __restrict__ Amat) {
  __shared__ __align__(16) char As[16384];
  __shared__ __align__(16) char Bs1[16384];
  __shared__ __align__(16) char Bs2[16384];
  const int tid = threadIdx.x;
  const int wave = tid >> 6, lane = tid & 63;
  const int bm = blockIdx.x * 128, bn = blockIdx.y * 128;
  f32x4 acc1[4][4] = {}, acc2[4][4] = {};
  const int fm = lane & 15, fk = (lane >> 4) * 8;
  const int wm = (wave >> 1) * 64, wn = (wave & 1) * 64;

  for (int k0 = 0; k0 < 2048; k0 += 64) {
    stage_b(A, As, bm, 2048, k0, 1 << 30, tid);
    stage_b(B1, Bs1, bn, 2048, k0, 1 << 30, tid);
    stage_b(B2, Bs2, bn, 2048, k0, 1 << 30, tid);
    __builtin_amdgcn_s_waitcnt(0);
    __syncthreads();
#pragma unroll
    for (int ks = 0; ks < 2; ++ks) {
      const int ko = ks * 32 + fk;
      bf16x8 ah[4], b1f[4], b2f[4];
#pragma unroll
      for (int i = 0; i < 4; ++i) ah[i] = frag_b(As, wm + 16 * i + fm, ko);
#pragma unroll
      for (int j = 0; j < 4; ++j) b1f[j] = frag_b(Bs1, wn + 16 * j + fm, ko);
#pragma unroll
      for (int j = 0; j < 4; ++j) b2f[j] = frag_b(Bs2, wn + 16 * j + fm, ko);
#pragma unroll
      for (int i = 0; i < 4; ++i)
#pragma unroll
        for (int j = 0; j < 4; ++j) {
          acc1[i][j] = __builtin_amdgcn_mfma_f32_16x16x32_bf16(
              ah[i], b1f[j], acc1[i][j], 0, 0, 0);
          acc2[i][j] = __builtin_amdgcn_mfma_f32_16x16x32_bf16(
              ah[i], b2f[j], acc2[i][j], 0, 0, 0);
        }
    }
    __syncthreads();
  }

  const int r0 = (lane >> 4) * 4;
#pragma unroll
  for (int i = 0; i < 4; ++i)
#pragma unroll
    for (int r = 0; r < 4; ++r) {
      const int row = bm + wm + 16 * i + r0 + r;
      const f32x4 a = *(const f32x4*)(Amat + (size_t)row * 4);  // a00,a10,a01,a11
#pragma unroll
      for (int j = 0; j < 4; ++j) {
        const int col = bn + wn + 16 * j + fm;
        float z = (float)Z0[(size_t)row * 2048 + col];
        float v = a[1] * acc1[i][j][r] + a[3] * acc2[i][j][r] + z;
        H[(size_t)row * 2048 + col] = (bf16)(v > 0.f ? v : 0.f);
      }
    }
}

// ---------------------------------------------------------------------------
__global__ void zero_k(float* __restrict__ p) {
  p[blockIdx.x * 256 + threadIdx.x] = 0.f;
}

// fp32 -> bf16 hi; used for fuse_w / fc_w
__global__ void cvt_k(const float* __restrict__ src, bf16* __restrict__ hi) {
  const size_t i = ((size_t)blockIdx.x * 256 + threadIdx.x) * 8;
  f32x4 a = *(const f32x4*)(src + i);
  f32x4 b = *(const f32x4*)(src + i + 4);
  bf16x8 h;
#pragma unroll
  for (int t = 0; t < 4; ++t) { h[t] = (bf16)a[t]; h[4 + t] = (bf16)b[t]; }
  *(bf16x8*)(hi + i) = h;
}

__device__ __forceinline__ float block_sum(float v, float* sbuf) {
#pragma unroll
  for (int o = 32; o > 0; o >>= 1) v += __shfl_down(v, o, 64);
  const int wave = threadIdx.x >> 6, lane = threadIdx.x & 63;
  if (lane == 0) sbuf[wave] = v;
  __syncthreads();
  float r = sbuf[0] + sbuf[1] + sbuf[2] + sbuf[3];
  __syncthreads();
  return r;
}

// feat: one read -> featH, featL, row norm nx
__global__ void featcvt_k(const float* __restrict__ x, bf16* __restrict__ H,
                          bf16* __restrict__ L, float* __restrict__ nx) {
  __shared__ float sbuf[4];
  const size_t base = (size_t)blockIdx.x * 2048 + threadIdx.x * 8;
  f32x4 a = *(const f32x4*)(x + base);
  f32x4 b = *(const f32x4*)(x + base + 4);
  bf16x8 h, l;
  float s = 0.f;
#pragma unroll
  for (int t = 0; t < 4; ++t) {
    h[t] = (bf16)a[t]; h[4 + t] = (bf16)b[t];
    l[t] = (bf16)(a[t] - (float)h[t]);
    l[4 + t] = (bf16)(b[t] - (float)h[4 + t]);
    s += a[t] * a[t] + b[t] * b[t];
  }
  *(bf16x8*)(H + base) = h;
  *(bf16x8*)(L + base) = l;
  float tot = block_sum(s, sbuf);
  if (threadIdx.x == 0) nx[blockIdx.x] = fmaxf(sqrtf(tot), 1e-12f);
}

// emb: one read -> embH, embL, norm nw, normalized sq-sum sw
__global__ void embcvt_k(const float* __restrict__ x, bf16* __restrict__ H,
                         bf16* __restrict__ L, float* __restrict__ nw,
                         float* __restrict__ sw) {
  __shared__ float sbuf[4];
  const size_t base = (size_t)blockIdx.x * 2048 + threadIdx.x * 8;
  f32x4 a = *(const f32x4*)(x + base);
  f32x4 b = *(const f32x4*)(x + base + 4);
  bf16x8 h, l;
  float s = 0.f;
#pragma unroll
  for (int t = 0; t < 4; ++t) {
    h[t] = (bf16)a[t]; h[4 + t] = (bf16)b[t];
    l[t] = (bf16)(a[t] - (float)h[t]);
    l[4 + t] = (bf16)(b[t] - (float)h[4 + t]);
    s += a[t] * a[t] + b[t] * b[t];
  }
  *(bf16x8*)(H + base) = h;
  *(bf16x8*)(L + base) = l;
  float n = fmaxf(sqrtf(block_sum(s, sbuf)), 1e-12f);
  float s2 = 0.f;
#pragma unroll
  for (int t = 0; t < 4; ++t) {
    float va = a[t] / n, vb = b[t] / n;
    s2 += va * va + vb * vb;
  }
  float tot2 = block_sum(s2, sbuf);
  if (threadIdx.x == 0) { nw[blockIdx.x] = n; sw[blockIdx.x] = tot2; }
}

// Z0[b] = a00*T1[ix_b] + a01*T2[ix_b] + fuse_b   (row-contiguous table reads)
__global__ void zgather_k(const int* __restrict__ idxb,
                          const float* __restrict__ Amat,
                          const float* __restrict__ T1,
                          const float* __restrict__ T2,
                          const float* __restrict__ fb,
                          bf16* __restrict__ Z0) {
  const int b = blockIdx.x;
  const int ix = idxb[b];
  const float a00 = Amat[(size_t)b * 4 + 0];
  const float a01 = Amat[(size_t)b * 4 + 2];
  const int i = threadIdx.x * 8;
  const float* t1p = T1 + (size_t)ix * 2048 + i;
  const float* t2p = T2 + (size_t)ix * 2048 + i;
  f32x4 t1a = *(const f32x4*)t1p, t1b = *(const f32x4*)(t1p + 4);
  f32x4 t2a = *(const f32x4*)t2p, t2b = *(const f32x4*)(t2p + 4);
  f32x4 fba = *(const f32x4*)(fb + i), fbb = *(const f32x4*)(fb + i + 4);
  bf16x8 z;
#pragma unroll
  for (int t = 0; t < 4; ++t) {
    z[t] = (bf16)(a00 * t1a[t] + a01 * t2a[t] + fba[t]);
    z[4 + t] = (bf16)(a00 * t1b[t] + a01 * t2b[t] + fbb[t]);
  }
  *(bf16x8*)(Z0 + (size_t)b * 2048 + i) = z;
}

// fp32 2048x2048 transpose -> bf16 K-contiguous operands
__global__ void transpose3_k(const float* __restrict__ Kw,
                             const float* __restrict__ Qw,
                             const float* __restrict__ Vw,
                             bf16* __restrict__ KwT, bf16* __restrict__ QwT,
                             bf16* __restrict__ VwT) {
  __shared__ float tile[64][65];
  const int z = blockIdx.z;
  const float* src = z == 0 ? Kw : z == 1 ? Qw : Vw;
  bf16* dst = z == 0 ? KwT : z == 1 ? QwT : VwT;
  const int bx = blockIdx.x * 64, by = blockIdx.y * 64;
  const int tx = threadIdx.x & 63, ty = threadIdx.x >> 6;
  for (int r = ty; r < 64; r += 4)
    tile[r][tx] = src[(size_t)(by + r) * 2048 + bx + tx];
  __syncthreads();
  for (int r = ty; r < 64; r += 4)
    dst[(size_t)(bx + r) * 2048 + by + tx] = (bf16)tile[tx][r];
}

// bf16 2048x2048 transpose: GT = G^T
__global__ void transpose_g_k(const bf16* __restrict__ src,
                              bf16* __restrict__ dst) {
  __shared__ bf16 tile[64][65];
  const int bx = blockIdx.x * 64, by = blockIdx.y * 64;
  const int tx = threadIdx.x & 63, ty = threadIdx.x >> 6;
  for (int r = ty; r < 64; r += 4)
    tile[r][tx] = src[(size_t)(by + r) * 2048 + bx + tx];
  __syncthreads();
  for (int r = ty; r < 64; r += 4)
    dst[(size_t)(bx + r) * 2048 + by + tx] = tile[tx][r];
}

// reduce 8 column-block candidates -> final idx
__global__ void idx_sel_k(const float* __restrict__ Dmin,
                          const int* __restrict__ Darg, int* __restrict__ idxb,
                          float* __restrict__ out_idx) {
  const int b = blockIdx.x * 256 + threadIdx.x;
  float best = 3.4e38f;
  int idx = 0;
  bool found = false;
  for (int t = 0; t < 8; ++t) {
    float v = Dmin[(size_t)b * 8 + t];
    int a = Darg[(size_t)b * 8 + t];
    if (!(v == v) || a < 0 || a >= 1000) continue;
    if (!found || v < best || (v == best && a < idx)) {
      best = v; idx = a; found = true;
    }
  }
  if (idx < 0) idx = 0;
  if (idx > 999) idx = 999;
  idxb[b] = idx;
  out_idx[b] = (float)idx;
}

// t00[i] = e_i^T G e_i = dot(EG[i], emb[i])
__global__ void t00_k(const float* __restrict__ EG, const float* __restrict__ emb,
                      float* __restrict__ t00) {
  __shared__ float sbuf[4];
  const int i = blockIdx.x, t = threadIdx.x;
  const float* a = EG + (size_t)i * 2048;
  const float* e = emb + (size_t)i * 2048;
  f32x4 va = *(const f32x4*)(a + t * 8), vb = *(const f32x4*)(a + t * 8 + 4);
  f32x4 ea = *(const f32x4*)(e + t * 8), eb = *(const f32x4*)(e + t * 8 + 4);
  float s = 0.f;
#pragma unroll
  for (int u = 0; u < 4; ++u) s += va[u] * ea[u] + vb[u] * eb[u];
  float r = block_sum(s, sbuf);
  if (t == 0) t00[i] = r;
}

// s00 = t00[idx]; s01 = dot(EG[idx], f); s10 = dot(EGT[idx], f)
__global__ void score_gather_k(const float* __restrict__ feat,
                               const float* __restrict__ EG,
                               const float* __restrict__ EGT,
                               const float* __restrict__ t00,
                               const int* __restrict__ idxb,
                               float* __restrict__ s00, float* __restrict__ s10,
                               float* __restrict__ s01) {
  __shared__ float sbuf[4];
  const int b = blockIdx.x, t = threadIdx.x;
  const int ix = idxb[b];
  const float* f = feat + (size_t)b * 2048;
  const float* eg = EG + (size_t)ix * 2048;
  const float* eh = EGT + (size_t)ix * 2048;
  f32x4 fa = *(const f32x4*)(f + t * 8), fb2 = *(const f32x4*)(f + t * 8 + 4);
  f32x4 ga = *(const f32x4*)(eg + t * 8), gb = *(const f32x4*)(eg + t * 8 + 4);
  f32x4 ha = *(const f32x4*)(eh + t * 8), hb = *(const f32x4*)(eh + t * 8 + 4);
  float d01 = 0.f, d10 = 0.f;
#pragma unroll
  for (int u = 0; u < 4; ++u) {
    d01 += fa[u] * ga[u] + fb2[u] * gb[u];
    d10 += fa[u] * ha[u] + fb2[u] * hb[u];
  }
  float r01 = block_sum(d01, sbuf);
  float r10 = block_sum(d10, sbuf);
  if (t == 0) { s01[b] = r01; s10[b] = r10; s00[b] = t00[ix]; }
}

__global__ void scores_final_k(const float* __restrict__ s00p,
                               const float* __restrict__ s10p,
                               const float* __restrict__ s01p,
                               const float* __restrict__ s11p,
                               float* __restrict__ Amat) {
  const int b = blockIdx.x * 256 + threadIdx.x;
  float t00 = s00p[b], t10 = s10p[b], t01 = s01p[b], t11 = s11p[b];
  float m0 = fmaxf(t00, t10), m1 = fmaxf(t01, t11);
  float e00 = expf(t00 - m0), e10 = expf(t10 - m0);
  float e01 = expf(t01 - m1), e11 = expf(t11 - m1);
  float d0 = e00 + e10, d1 = e01 + e11;
  float* Ab = Amat + (size_t)b * 4;
  Ab[0] = e00 / d0; Ab[1] = e10 / d0; Ab[2] = e01 / d1; Ab[3] = e11 / d1;
}

// final out_q gather
__global__ void gather_q_k(const int* __restrict__ idxb,
                           const float* __restrict__ emb,
                           float* __restrict__ outq) {
  const int b = blockIdx.x;
  const int ix = idxb[b];
  const f32x4* src = (const f32x4*)(emb + (size_t)ix * 2048);
  f32x4* dst = (f32x4*)(outq + (size_t)b * 2048);
  dst[threadIdx.x] = src[threadIdx.x];
  dst[threadIdx.x + 256] = src[threadIdx.x + 256];
}

// ---------------------------------------------------------------------------
extern "C" void kernel_launch(void* const* d_in, const int* in_sizes, int n_in,
                              void* d_out, int out_size, void* d_ws,
                              size_t ws_size, hipStream_t stream) {
  const float* feat = (const float*)d_in[0];
  const float* emb = (const float*)d_in[1];
  const float* Kw = (const float*)d_in[2];
  const float* Qw = (const float*)d_in[3];
  const float* Vw = (const float*)d_in[4];
  const float* fuse_w = (const float*)d_in[5];
  const float* fuse_b = (const float*)d_in[6];
  const float* fc_w = (const float*)d_in[7];
  const float* fc_b = (const float*)d_in[8];

  float* out_q = (float*)d_out;                     // 8192*2048 f32 = 64 MiB
  float* out_pred = out_q + (size_t)8192 * 2048;    // 8192*1000 f32
  float* out_idx = out_pred + (size_t)8192 * 1000;  // 8192

  char* ws = (char*)d_ws;
  const size_t MiB = 1024 * 1024;
  float* nx = (float*)(ws + 0);           // 32 KB
  float* nw = (float*)(ws + 32768);       // 4 KB
  float* swp = (float*)(ws + 36864);      // 4 KB
  float* t00 = (float*)(ws + 40960);      // 4 KB
  int* idxb = (int*)(ws + 45056);         // 32 KB
  float* s00 = (float*)(ws + 81920);      // 32 KB
  float* s10 = (float*)(ws + 114688);     // 32 KB
  float* s01 = (float*)(ws + 147456);     // 32 KB
  float* s11 = (float*)(ws + 180224);     // 32 KB
  float* Amat = (float*)(ws + 212992);    // 128 KB
  float* Dmin = (float*)(ws + 360448);    // 256 KB (8192x8)
  int* Darg = (int*)(ws + 622592);        // 256 KB -> ends < 1 MiB
  bf16* G = (bf16*)(ws + 1 * MiB);        // 8 MiB [1,9)   live: big4..s11
  bf16* GT = (bf16*)(ws + 9 * MiB);       // 8 MiB [9,17)  live: transpose..emb4
  bf16* M1 = (bf16*)(ws + 17 * MiB);      // 8 MiB [17,25) live: big4..gemm_h
  bf16* M2 = (bf16*)(ws + 25 * MiB);      // 8 MiB [25,33) live: big4..gemm_h
  // reuse after GT dead (post-emb4):
  bf16* embH = (bf16*)(ws + 9 * MiB);               // 4,096,000 B
  bf16* embL = (bf16*)(ws + 9 * MiB + 4096000);     // 4,096,000 B
  // reuse after M1 dead (post-gemm_h):
  bf16* fc_wB = (bf16*)(ws + 17 * MiB);             // 4,096,000 B

  // out_q region as scratch:
  char* oq = (char*)out_q;
  bf16* KwT = (bf16*)oq;                   // [0,8)  MiB  dead after big4
  bf16* QwT = (bf16*)(oq + 8 * MiB);       // [8,16) MiB  dead after big4
  bf16* VwT = (bf16*)(oq + 16 * MiB);      // [16,24) MiB dead after big4
  bf16* fuse_wB = (bf16*)(oq + 24 * MiB);  // [24,40) MiB dead after big4
  bf16* featH = (bf16*)oq;                 // [0,32) MiB  (post-big4..gemm_h A)
  bf16* featL = (bf16*)(oq + 32 * MiB);    // [32,64) MiB (post-big4..dist)
  bf16* Z0 = (bf16*)(oq + 32 * MiB);       // [32,64) MiB (zgather..gemm_h)
  bf16* Hbuf = Z0;                         // in-place over Z0 (gemm_h..pred)

  // out_pred region: EG|EGT|T1|T2 = 4 x 8,192,000 B (exact fit)
  float* EG = out_pred;
  float* EGT = out_pred + (size_t)2048 * 1000;
  float* T1 = out_pred + (size_t)4096 * 1000;
  float* T2 = out_pred + (size_t)6144 * 1000;

  // --- setup passes ---
  zero_k<<<32, 256, 0, stream>>>(s11);
  transpose3_k<<<dim3(32, 32, 3), 256, 0, stream>>>(Kw, Qw, Vw, KwT, QwT, VwT);
  cvt_k<<<4096, 256, 0, stream>>>(fuse_w, fuse_wB);  // 2048x4096

  // big3 (768 wg): G=Kw^T Qw, M1=W1 Vw, M2=W2 Vw (all-bf16 A)
  gemm4_nt<false, false, 4><<<dim3(16, 16, 3), 256, 0, stream>>>(
      KwT, fuse_wB, fuse_wB + 2048, nullptr, QwT, VwT, VwT, nullptr, G, M1, M2,
      nullptr, 2048, 2048, 4096, 2048, 2048, 1 << 30);

  // GT = G^T (bf16 transpose; replaces the former 2048^3 GEMM)
  transpose_g_k<<<dim3(32, 32), 256, 0, stream>>>(G, GT);

  // emb4 (512 wg): EG=emb@G, EGT=emb@G^T, T1=emb@M1^T, T2=emb@M2^T (A fp32)
  gemm4_nt<true, true, 3><<<dim3(8, 16, 4), 256, 0, stream>>>(
      emb, emb, emb, emb, GT, G, M1, M2, EG, EGT, T1, T2, 2048, 2048, 2048,
      2048, 2048, 999);
  t00_k<<<1000, 256, 0, stream>>>(EG, emb, t00);

  // fused norm+convert passes (KwT/QwT/VwT/fuse_wB and GT now dead)
  featcvt_k<<<8192, 256, 0, stream>>>(feat, featH, featL, nx);
  embcvt_k<<<1000, 256, 0, stream>>>(emb, embH, embL, nw, swp);

  // full-batch distance GEMM (512 wg, hi/lo triple) + argmin
  gemm_nt<EPI_DIST, true, 2><<<dim3(64, 8), 256, 0, stream>>>(
      featH, featL, embH, embL, nullptr, nullptr, nullptr, nullptr, nx, nw,
      swp, Dmin, Darg, 2048, 2048, 2048, 0, 999);
  idx_sel_k<<<32, 256, 0, stream>>>(Dmin, Darg, idxb, out_idx);
  score_gather_k<<<8192, 256, 0, stream>>>(feat, EG, EGT, t00, idxb, s00, s10,
                                           s01);

  // s11 = f^T G f (1024 wg) with fused row-dot epilogue
  gemm_nt<EPI_SCORES, false, 4><<<dim3(64, 16), 256, 0, stream>>>(
      featH, nullptr, G, nullptr, nullptr, nullptr, feat, s11, nullptr,
      nullptr, nullptr, nullptr, nullptr, 2048, 2048, 2048, 0, 2047);
  scores_final_k<<<32, 256, 0, stream>>>(s00, s10, s01, s11, Amat);

  // Z0 = a00*T1[ix] + a01*T2[ix] + fuse_b  (row-contiguous; overwrites featL)
  zgather_k<<<8192, 256, 0, stream>>>(idxb, Amat, T1, T2, fuse_b, Z0);

  // h = relu(a10*featH@M1^T + a11*featH@M2^T + Z0)  (all-bf16; H in-place)
  gemm_h<<<dim3(64, 16), 256, 0, stream>>>(featH, M1, M2, Hbuf, Z0, Amat);

  // fc_w -> bf16 (into ex-M1; M1 dead after gemm_h)
  cvt_k<<<1000, 256, 0, stream>>>(fc_w, fc_wB);

  // pred (512 wg): fp32 out, ragged N=1000 (overwrites EG/EGT/T1/T2 — dead)
  gemm_nt<EPI_BIAS, false, 4><<<dim3(64, 8), 256, 0, stream>>>(
      Hbuf, nullptr, fc_wB, nullptr, out_pred, fc_b, nullptr, nullptr, nullptr,
      nullptr, nullptr, nullptr, nullptr, 2048, 2048, 2048, 1000, 999);

  // final out_q gather (featH/Hbuf scratch dead)
  gather_q_k<<<8192, 256, 0, stream>>>(idxb, emb, out_q);
}

// Round 6
// 776.201 us; speedup vs baseline: 1.4069x; 1.4069x over previous
//
#include <hip/hip_runtime.h>
#include <cstdint>
#include <cstddef>

// ============================================================================
// new_clsnet on MI355X — round 10: resubmit r9 (infra failure, no verdict).
// r9 = r8 + gemm_h __launch_bounds__(256,3)->(256,2) to fix the VGPR spill:
// r6 & r8 gemm_h both (256,3) -> VGPR_Count 84 -> accumulator spill to
// scratch (FETCH/WRITE +~500MB, MfmaUtil ~12%, 450-490us). r7 at (256,2) ->
// 124 VGPR -> 143us. s11 reads the same featH-from-d_out A with no pathology
// => location was a red herring; the spill was the cost.
// gemm_h: all-bf16 (no in-loop cvt), 48K LDS (3 blk/CU LDS-limited), H
// written in-place over Z0 (saves the 32MiB write-allocate RFO).
// Memory map:
//   ws[1,9) G | ws[9,17) GT -> embH/embL | ws[17,25) M1 -> fc_wB | ws[25,33) M2
//   oq[0,24) KwT/QwT/VwT, oq[24,40) fuse_wB (dead after big3)
//   then oq[0,32MiB) featH (live..gemm_h) | oq[32,64) featL -> Z0 -> H(inplace)
//   out_pred = EG|EGT|T1|T2 (exact fit) until pred overwrites.
// ============================================================================

typedef __bf16 bf16;
typedef __bf16 bf16x8 __attribute__((ext_vector_type(8)));
typedef float  f32x4  __attribute__((ext_vector_type(4)));

#define TO_AS1(p) ((__attribute__((address_space(1))) void*)(uintptr_t)(p))
#define TO_AS3(p) ((__attribute__((address_space(3))) void*)(uintptr_t)(p))

enum { EPI_DIST = 1, EPI_SCORES = 2, EPI_BIAS = 4 };

// ---- staging: 128x64-elem tile, linear LDS dest, XOR-swizzled global src ---
// LDS position chunk p (16B) holds source chunk (p%CPR)^(rloc&7) of row rloc.
__device__ __forceinline__ void stage_b(const bf16* __restrict__ src, char* lds,
                                        int rbase, int ld, int k0, int clamp,
                                        int tid) {
  const int wb = tid & ~63, lane = tid & 63;
#pragma unroll
  for (int it = 0; it < 4; ++it) {
    const int chunk = it * 256 + wb + lane;
    const int rloc = chunk >> 3;  // 8 chunks per 64-elem bf16 row
    int row = rbase + rloc;
    if (row > clamp) row = clamp;
    const int sc = (chunk & 7) ^ (rloc & 7);
    const bf16* gp = src + (size_t)row * ld + k0 + sc * 8;
    __builtin_amdgcn_global_load_lds(TO_AS1(gp),
                                     TO_AS3(lds + (it * 256 + wb) * 16), 16, 0,
                                     0);
  }
}

__device__ __forceinline__ void stage_f(const float* __restrict__ src,
                                        char* lds, int rbase, int ld, int k0,
                                        int clamp, int tid) {
  const int wb = tid & ~63, lane = tid & 63;
#pragma unroll
  for (int it = 0; it < 8; ++it) {
    const int chunk = it * 256 + wb + lane;
    const int rloc = chunk >> 4;  // 16 chunks per 64-elem fp32 row
    int row = rbase + rloc;
    if (row > clamp) row = clamp;
    const int sc = (chunk & 15) ^ (rloc & 7);
    const float* gp = src + (size_t)row * ld + k0 + sc * 4;
    __builtin_amdgcn_global_load_lds(TO_AS1(gp),
                                     TO_AS3(lds + (it * 256 + wb) * 16), 16, 0,
                                     0);
  }
}

// ---- fragment loads (apply the same XOR on the read address) --------------
__device__ __forceinline__ bf16x8 frag_b(const char* lds, int r, int koff) {
  const int cc = (koff >> 3) ^ (r & 7);
  return *(const bf16x8*)(lds + r * 128 + cc * 16);
}

__device__ __forceinline__ bf16x8 frag_f(const char* lds, int r, int koff) {
  const int c0 = koff >> 2;  // even
  const f32x4 v0 = *(const f32x4*)(lds + r * 256 + ((c0 ^ (r & 7)) << 4));
  const f32x4 v1 =
      *(const f32x4*)(lds + r * 256 + (((c0 + 1) ^ (r & 7)) << 4));
  bf16x8 h;
#pragma unroll
  for (int t = 0; t < 4; ++t) { h[t] = (bf16)v0[t]; h[4 + t] = (bf16)v1[t]; }
  return h;
}

// ---------------------------------------------------------------------------
// C[m,n] = sum_k A[m,k]*B[n,k]; 128x128 tile, BK=64, 256 thr, mfma 16x16x32.
// All operands bf16 (pre-converted). TRIPLE: A/B given as hi+lo pairs,
// acc += AH*BH + AH*BL + AL*BH (fp32-grade for argmin).
// ---------------------------------------------------------------------------
template <int EPI, bool TRIPLE, int MINW>
__global__ __launch_bounds__(256, MINW) void gemm_nt(
    const bf16* __restrict__ AH, const bf16* __restrict__ AL,
    const bf16* __restrict__ BH, const bf16* __restrict__ BL,
    void* __restrict__ Cout, const float* __restrict__ bias,
    const float* __restrict__ qp, float* __restrict__ sA,
    const float* __restrict__ nx, const float* __restrict__ nw,
    const float* __restrict__ sw, float* __restrict__ Dmin,
    int* __restrict__ Darg, int K, int lda, int ldb, int ldc, int nclamp) {
  __shared__ __align__(16) char AsH[16384];
  __shared__ __align__(16) char BsH[16384];
  __shared__ __align__(16) char AsL[TRIPLE ? 16384 : 16];
  __shared__ __align__(16) char BsL[TRIPLE ? 16384 : 16];

  const int tid = threadIdx.x;
  const int wave = tid >> 6, lane = tid & 63;
  const int bm = blockIdx.x * 128, bn = blockIdx.y * 128;

  f32x4 acc[4][4] = {};

  const int fm = lane & 15;
  const int fk = (lane >> 4) * 8;
  const int wm = (wave >> 1) * 64;
  const int wn = (wave & 1) * 64;

  for (int k0 = 0; k0 < K; k0 += 64) {
    stage_b(AH, AsH, bm, lda, k0, 1 << 30, tid);
    stage_b(BH, BsH, bn, ldb, k0, nclamp, tid);
    if constexpr (TRIPLE) {
      stage_b(AL, AsL, bm, lda, k0, 1 << 30, tid);
      stage_b(BL, BsL, bn, ldb, k0, nclamp, tid);
    }
    __builtin_amdgcn_s_waitcnt(0);
    __syncthreads();
#pragma unroll
    for (int ks = 0; ks < 2; ++ks) {
      const int ko = ks * 32 + fk;
      bf16x8 ah[4], bh[4];
#pragma unroll
      for (int i = 0; i < 4; ++i) ah[i] = frag_b(AsH, wm + 16 * i + fm, ko);
#pragma unroll
      for (int j = 0; j < 4; ++j) bh[j] = frag_b(BsH, wn + 16 * j + fm, ko);
      if constexpr (TRIPLE) {
        bf16x8 al[4], bl[4];
#pragma unroll
        for (int i = 0; i < 4; ++i) al[i] = frag_b(AsL, wm + 16 * i + fm, ko);
#pragma unroll
        for (int j = 0; j < 4; ++j) bl[j] = frag_b(BsL, wn + 16 * j + fm, ko);
#pragma unroll
        for (int i = 0; i < 4; ++i)
#pragma unroll
          for (int j = 0; j < 4; ++j) {
            acc[i][j] = __builtin_amdgcn_mfma_f32_16x16x32_bf16(
                ah[i], bh[j], acc[i][j], 0, 0, 0);
            acc[i][j] = __builtin_amdgcn_mfma_f32_16x16x32_bf16(
                ah[i], bl[j], acc[i][j], 0, 0, 0);
            acc[i][j] = __builtin_amdgcn_mfma_f32_16x16x32_bf16(
                al[i], bh[j], acc[i][j], 0, 0, 0);
          }
      } else {
#pragma unroll
        for (int i = 0; i < 4; ++i)
#pragma unroll
          for (int j = 0; j < 4; ++j)
            acc[i][j] = __builtin_amdgcn_mfma_f32_16x16x32_bf16(
                ah[i], bh[j], acc[i][j], 0, 0, 0);
      }
    }
    __syncthreads();
  }

  // epilogue; C/D layout: col=lane&15, row=(lane>>4)*4+r (m89-verified)
  const int r0 = (lane >> 4) * 4;

  if constexpr (EPI == EPI_DIST) {
    __shared__ float vred[256];
    __shared__ int ared[256];
    const float INF = 3.4e38f;
#pragma unroll
    for (int i = 0; i < 4; ++i) {
#pragma unroll
      for (int r = 0; r < 4; ++r) {
        const int rl = wm + 16 * i + r0 + r;
        const float rx = nx[bm + rl];
        float best = INF;
        int barg = 0;
#pragma unroll
        for (int j = 0; j < 4; ++j) {
          const int col = bn + wn + 16 * j + fm;
          if (col <= nclamp) {
            float s = sw[col] - 2.0f * acc[i][j][r] / (rx * nw[col]);
            if (s < best) { best = s; barg = col; }
          }
        }
#pragma unroll
        for (int o = 8; o >= 1; o >>= 1) {
          float ob = __shfl_xor(best, o, 64);
          int oa = __shfl_xor(barg, o, 64);
          if (ob < best || (ob == best && oa < barg)) { best = ob; barg = oa; }
        }
        if (fm == 0) {
          vred[rl * 2 + (wave & 1)] = best;
          ared[rl * 2 + (wave & 1)] = barg;
        }
      }
    }
    __syncthreads();
    if (tid < 128) {
      float v0 = vred[tid * 2], v1 = vred[tid * 2 + 1];
      int a0 = ared[tid * 2], a1 = ared[tid * 2 + 1];
      float bv = v0; int ba = a0;
      if (v1 < bv || (v1 == bv && a1 < ba)) { bv = v1; ba = a1; }
      Dmin[(size_t)(bm + tid) * 8 + blockIdx.y] = bv;
      Darg[(size_t)(bm + tid) * 8 + blockIdx.y] = ba;
    }
    return;
  }

  if constexpr (EPI == EPI_SCORES) {
#pragma unroll
    for (int i = 0; i < 4; ++i) {
#pragma unroll
      for (int r = 0; r < 4; ++r) {
        const int row = bm + wm + 16 * i + r0 + r;
        float pa = 0.f;
#pragma unroll
        for (int j = 0; j < 4; ++j) {
          const int col = bn + wn + 16 * j + fm;
          pa += qp[(size_t)row * 2048 + col] * acc[i][j][r];
        }
#pragma unroll
        for (int o = 8; o >= 1; o >>= 1) pa += __shfl_xor(pa, o, 64);
        if (fm == 0) atomicAdd(&sA[row], pa);
      }
    }
    return;
  }

  // EPI_BIAS: fp32 out, ragged-guarded cols
#pragma unroll
  for (int i = 0; i < 4; ++i)
#pragma unroll
    for (int j = 0; j < 4; ++j) {
      const int col = bn + wn + 16 * j + fm;
#pragma unroll
      for (int r = 0; r < 4; ++r) {
        const int row = bm + wm + 16 * i + r0 + r;
        int bc = col <= nclamp ? col : nclamp;
        float v = acc[i][j][r] + bias[bc];
        if (col <= nclamp) ((float*)Cout)[(size_t)row * ldc + col] = v;
      }
    }
}

// ---------------------------------------------------------------------------
// z-batched 4-GEMM. AF32: A operands fp32-staged (emb4); else bf16.
// lda: z==0 -> lda0, else ldaR.
// ---------------------------------------------------------------------------
template <bool AF32, bool F32OUT, int MINW>
__global__ __launch_bounds__(256, MINW) void gemm4_nt(
    const void* a0, const void* a1, const void* a2, const void* a3,
    const bf16* b0, const bf16* b1, const bf16* b2, const bf16* b3, void* c0,
    void* c1, void* c2, void* c3, int K, int lda0, int ldaR, int ldb,
    int ldc, int mclamp) {
  __shared__ __align__(16) char AsRaw[AF32 ? 32768 : 16384];
  __shared__ __align__(16) char BsRaw[16384];
  const int z = blockIdx.z;
  const void* A = z == 0 ? a0 : z == 1 ? a1 : z == 2 ? a2 : a3;
  const bf16* B = z == 0 ? b0 : z == 1 ? b1 : z == 2 ? b2 : b3;
  void* C = z == 0 ? c0 : z == 1 ? c1 : z == 2 ? c2 : c3;
  const int lda = (z == 0) ? lda0 : ldaR;

  const int tid = threadIdx.x;
  const int wave = tid >> 6, lane = tid & 63;
  const int bm = blockIdx.x * 128, bn = blockIdx.y * 128;
  f32x4 acc[4][4] = {};
  const int fm = lane & 15, fk = (lane >> 4) * 8;
  const int wm = (wave >> 1) * 64, wn = (wave & 1) * 64;

  for (int k0 = 0; k0 < K; k0 += 64) {
    if constexpr (AF32)
      stage_f((const float*)A, AsRaw, bm, lda, k0, mclamp, tid);
    else
      stage_b((const bf16*)A, AsRaw, bm, lda, k0, mclamp, tid);
    stage_b(B, BsRaw, bn, ldb, k0, 1 << 30, tid);
    __builtin_amdgcn_s_waitcnt(0);
    __syncthreads();
#pragma unroll
    for (int ks = 0; ks < 2; ++ks) {
      const int ko = ks * 32 + fk;
      bf16x8 ah[4], bh[4];
#pragma unroll
      for (int i = 0; i < 4; ++i)
        ah[i] = AF32 ? frag_f(AsRaw, wm + 16 * i + fm, ko)
                     : frag_b(AsRaw, wm + 16 * i + fm, ko);
#pragma unroll
      for (int j = 0; j < 4; ++j) bh[j] = frag_b(BsRaw, wn + 16 * j + fm, ko);
#pragma unroll
      for (int i = 0; i < 4; ++i)
#pragma unroll
        for (int j = 0; j < 4; ++j)
          acc[i][j] = __builtin_amdgcn_mfma_f32_16x16x32_bf16(ah[i], bh[j],
                                                              acc[i][j], 0, 0, 0);
    }
    __syncthreads();
  }

  const int r0 = (lane >> 4) * 4;
#pragma unroll
  for (int i = 0; i < 4; ++i)
#pragma unroll
    for (int j = 0; j < 4; ++j) {
      const int col = bn + wn + 16 * j + fm;
#pragma unroll
      for (int r = 0; r < 4; ++r) {
        const int row = bm + wm + 16 * i + r0 + r;
        if (row <= mclamp) {
          if constexpr (F32OUT)
            ((float*)C)[(size_t)row * ldc + col] = acc[i][j][r];
          else
            ((bf16*)C)[(size_t)row * ldc + col] = (bf16)acc[i][j][r];
        }
      }
    }
}

// ---------------------------------------------------------------------------
// dual-B h-GEMM: acc1=featH@M1^T, acc2=featH@M2^T (all-bf16), fused epilogue
// h = relu(a10*acc1 + a11*acc2 + Z0[row][col]); H written in-place over Z0.
// MINW=2: r6/r8 showed MINW=3 caps VGPR at 84 -> accumulator scratch spill
// (FETCH/WRITE +500MB, 450us). At MINW=2 the kernel gets ~110-124 VGPR,
// still 3 blk/CU via the 48K LDS limit.
// ---------------------------------------------------------------------------
__global__ __launch_bounds__(256, 2) void gemm_h(
    const bf16* __restrict__ A, const bf16* __restrict__ B1,
    const bf16* __restrict__ B2, bf16* __restrict__ H,
    const bf16* __restrict__ Z0, const float* __restrict__ Amat) {
  __shared__ __align__(16) char As[16384];
  __shared__ __align__(16) char Bs1[16384];
  __shared__ __align__(16) char Bs2[16384];
  const int tid = threadIdx.x;
  const int wave = tid >> 6, lane = tid & 63;
  const int bm = blockIdx.x * 128, bn = blockIdx.y * 128;
  f32x4 acc1[4][4] = {}, acc2[4][4] = {};
  const int fm = lane & 15, fk = (lane >> 4) * 8;
  const int wm = (wave >> 1) * 64, wn = (wave & 1) * 64;

  for (int k0 = 0; k0 < 2048; k0 += 64) {
    stage_b(A, As, bm, 2048, k0, 1 << 30, tid);
    stage_b(B1, Bs1, bn, 2048, k0, 1 << 30, tid);
    stage_b(B2, Bs2, bn, 2048, k0, 1 << 30, tid);
    __builtin_amdgcn_s_waitcnt(0);
    __syncthreads();
#pragma unroll
    for (int ks = 0; ks < 2; ++ks) {
      const int ko = ks * 32 + fk;
      bf16x8 ah[4], b1f[4], b2f[4];
#pragma unroll
      for (int i = 0; i < 4; ++i) ah[i] = frag_b(As, wm + 16 * i + fm, ko);
#pragma unroll
      for (int j = 0; j < 4; ++j) b1f[j] = frag_b(Bs1, wn + 16 * j + fm, ko);
#pragma unroll
      for (int j = 0; j < 4; ++j) b2f[j] = frag_b(Bs2, wn + 16 * j + fm, ko);
#pragma unroll
      for (int i = 0; i < 4; ++i)
#pragma unroll
        for (int j = 0; j < 4; ++j) {
          acc1[i][j] = __builtin_amdgcn_mfma_f32_16x16x32_bf16(
              ah[i], b1f[j], acc1[i][j], 0, 0, 0);
          acc2[i][j] = __builtin_amdgcn_mfma_f32_16x16x32_bf16(
              ah[i], b2f[j], acc2[i][j], 0, 0, 0);
        }
    }
    __syncthreads();
  }

  const int r0 = (lane >> 4) * 4;
#pragma unroll
  for (int i = 0; i < 4; ++i)
#pragma unroll
    for (int r = 0; r < 4; ++r) {
      const int row = bm + wm + 16 * i + r0 + r;
      const f32x4 a = *(const f32x4*)(Amat + (size_t)row * 4);  // a00,a10,a01,a11
#pragma unroll
      for (int j = 0; j < 4; ++j) {
        const int col = bn + wn + 16 * j + fm;
        float z = (float)Z0[(size_t)row * 2048 + col];
        float v = a[1] * acc1[i][j][r] + a[3] * acc2[i][j][r] + z;
        H[(size_t)row * 2048 + col] = (bf16)(v > 0.f ? v : 0.f);
      }
    }
}

// ---------------------------------------------------------------------------
__global__ void zero_k(float* __restrict__ p) {
  p[blockIdx.x * 256 + threadIdx.x] = 0.f;
}

// fp32 -> bf16 hi; used for fuse_w / fc_w
__global__ void cvt_k(const float* __restrict__ src, bf16* __restrict__ hi) {
  const size_t i = ((size_t)blockIdx.x * 256 + threadIdx.x) * 8;
  f32x4 a = *(const f32x4*)(src + i);
  f32x4 b = *(const f32x4*)(src + i + 4);
  bf16x8 h;
#pragma unroll
  for (int t = 0; t < 4; ++t) { h[t] = (bf16)a[t]; h[4 + t] = (bf16)b[t]; }
  *(bf16x8*)(hi + i) = h;
}

__device__ __forceinline__ float block_sum(float v, float* sbuf) {
#pragma unroll
  for (int o = 32; o > 0; o >>= 1) v += __shfl_down(v, o, 64);
  const int wave = threadIdx.x >> 6, lane = threadIdx.x & 63;
  if (lane == 0) sbuf[wave] = v;
  __syncthreads();
  float r = sbuf[0] + sbuf[1] + sbuf[2] + sbuf[3];
  __syncthreads();
  return r;
}

// feat: one read -> featH, featL, row norm nx
__global__ void featcvt_k(const float* __restrict__ x, bf16* __restrict__ H,
                          bf16* __restrict__ L, float* __restrict__ nx) {
  __shared__ float sbuf[4];
  const size_t base = (size_t)blockIdx.x * 2048 + threadIdx.x * 8;
  f32x4 a = *(const f32x4*)(x + base);
  f32x4 b = *(const f32x4*)(x + base + 4);
  bf16x8 h, l;
  float s = 0.f;
#pragma unroll
  for (int t = 0; t < 4; ++t) {
    h[t] = (bf16)a[t]; h[4 + t] = (bf16)b[t];
    l[t] = (bf16)(a[t] - (float)h[t]);
    l[4 + t] = (bf16)(b[t] - (float)h[4 + t]);
    s += a[t] * a[t] + b[t] * b[t];
  }
  *(bf16x8*)(H + base) = h;
  *(bf16x8*)(L + base) = l;
  float tot = block_sum(s, sbuf);
  if (threadIdx.x == 0) nx[blockIdx.x] = fmaxf(sqrtf(tot), 1e-12f);
}

// emb: one read -> embH, embL, norm nw, normalized sq-sum sw
__global__ void embcvt_k(const float* __restrict__ x, bf16* __restrict__ H,
                         bf16* __restrict__ L, float* __restrict__ nw,
                         float* __restrict__ sw) {
  __shared__ float sbuf[4];
  const size_t base = (size_t)blockIdx.x * 2048 + threadIdx.x * 8;
  f32x4 a = *(const f32x4*)(x + base);
  f32x4 b = *(const f32x4*)(x + base + 4);
  bf16x8 h, l;
  float s = 0.f;
#pragma unroll
  for (int t = 0; t < 4; ++t) {
    h[t] = (bf16)a[t]; h[4 + t] = (bf16)b[t];
    l[t] = (bf16)(a[t] - (float)h[t]);
    l[4 + t] = (bf16)(b[t] - (float)h[4 + t]);
    s += a[t] * a[t] + b[t] * b[t];
  }
  *(bf16x8*)(H + base) = h;
  *(bf16x8*)(L + base) = l;
  float n = fmaxf(sqrtf(block_sum(s, sbuf)), 1e-12f);
  float s2 = 0.f;
#pragma unroll
  for (int t = 0; t < 4; ++t) {
    float va = a[t] / n, vb = b[t] / n;
    s2 += va * va + vb * vb;
  }
  float tot2 = block_sum(s2, sbuf);
  if (threadIdx.x == 0) { nw[blockIdx.x] = n; sw[blockIdx.x] = tot2; }
}

// Z0[b] = a00*T1[ix_b] + a01*T2[ix_b] + fuse_b   (row-contiguous table reads)
__global__ void zgather_k(const int* __restrict__ idxb,
                          const float* __restrict__ Amat,
                          const float* __restrict__ T1,
                          const float* __restrict__ T2,
                          const float* __restrict__ fb,
                          bf16* __restrict__ Z0) {
  const int b = blockIdx.x;
  const int ix = idxb[b];
  const float a00 = Amat[(size_t)b * 4 + 0];
  const float a01 = Amat[(size_t)b * 4 + 2];
  const int i = threadIdx.x * 8;
  const float* t1p = T1 + (size_t)ix * 2048 + i;
  const float* t2p = T2 + (size_t)ix * 2048 + i;
  f32x4 t1a = *(const f32x4*)t1p, t1b = *(const f32x4*)(t1p + 4);
  f32x4 t2a = *(const f32x4*)t2p, t2b = *(const f32x4*)(t2p + 4);
  f32x4 fba = *(const f32x4*)(fb + i), fbb = *(const f32x4*)(fb + i + 4);
  bf16x8 z;
#pragma unroll
  for (int t = 0; t < 4; ++t) {
    z[t] = (bf16)(a00 * t1a[t] + a01 * t2a[t] + fba[t]);
    z[4 + t] = (bf16)(a00 * t1b[t] + a01 * t2b[t] + fbb[t]);
  }
  *(bf16x8*)(Z0 + (size_t)b * 2048 + i) = z;
}

// fp32 2048x2048 transpose -> bf16 K-contiguous operands
__global__ void transpose3_k(const float* __restrict__ Kw,
                             const float* __restrict__ Qw,
                             const float* __restrict__ Vw,
                             bf16* __restrict__ KwT, bf16* __restrict__ QwT,
                             bf16* __restrict__ VwT) {
  __shared__ float tile[64][65];
  const int z = blockIdx.z;
  const float* src = z == 0 ? Kw : z == 1 ? Qw : Vw;
  bf16* dst = z == 0 ? KwT : z == 1 ? QwT : VwT;
  const int bx = blockIdx.x * 64, by = blockIdx.y * 64;
  const int tx = threadIdx.x & 63, ty = threadIdx.x >> 6;
  for (int r = ty; r < 64; r += 4)
    tile[r][tx] = src[(size_t)(by + r) * 2048 + bx + tx];
  __syncthreads();
  for (int r = ty; r < 64; r += 4)
    dst[(size_t)(bx + r) * 2048 + by + tx] = (bf16)tile[tx][r];
}

// bf16 2048x2048 transpose: GT = G^T
__global__ void transpose_g_k(const bf16* __restrict__ src,
                              bf16* __restrict__ dst) {
  __shared__ bf16 tile[64][65];
  const int bx = blockIdx.x * 64, by = blockIdx.y * 64;
  const int tx = threadIdx.x & 63, ty = threadIdx.x >> 6;
  for (int r = ty; r < 64; r += 4)
    tile[r][tx] = src[(size_t)(by + r) * 2048 + bx + tx];
  __syncthreads();
  for (int r = ty; r < 64; r += 4)
    dst[(size_t)(bx + r) * 2048 + by + tx] = tile[tx][r];
}

// reduce 8 column-block candidates -> final idx
__global__ void idx_sel_k(const float* __restrict__ Dmin,
                          const int* __restrict__ Darg, int* __restrict__ idxb,
                          float* __restrict__ out_idx) {
  const int b = blockIdx.x * 256 + threadIdx.x;
  float best = 3.4e38f;
  int idx = 0;
  bool found = false;
  for (int t = 0; t < 8; ++t) {
    float v = Dmin[(size_t)b * 8 + t];
    int a = Darg[(size_t)b * 8 + t];
    if (!(v == v) || a < 0 || a >= 1000) continue;
    if (!found || v < best || (v == best && a < idx)) {
      best = v; idx = a; found = true;
    }
  }
  if (idx < 0) idx = 0;
  if (idx > 999) idx = 999;
  idxb[b] = idx;
  out_idx[b] = (float)idx;
}

// t00[i] = e_i^T G e_i = dot(EG[i], emb[i])
__global__ void t00_k(const float* __restrict__ EG, const float* __restrict__ emb,
                      float* __restrict__ t00) {
  __shared__ float sbuf[4];
  const int i = blockIdx.x, t = threadIdx.x;
  const float* a = EG + (size_t)i * 2048;
  const float* e = emb + (size_t)i * 2048;
  f32x4 va = *(const f32x4*)(a + t * 8), vb = *(const f32x4*)(a + t * 8 + 4);
  f32x4 ea = *(const f32x4*)(e + t * 8), eb = *(const f32x4*)(e + t * 8 + 4);
  float s = 0.f;
#pragma unroll
  for (int u = 0; u < 4; ++u) s += va[u] * ea[u] + vb[u] * eb[u];
  float r = block_sum(s, sbuf);
  if (t == 0) t00[i] = r;
}

// s00 = t00[idx]; s01 = dot(EG[idx], f); s10 = dot(EGT[idx], f)
__global__ void score_gather_k(const float* __restrict__ feat,
                               const float* __restrict__ EG,
                               const float* __restrict__ EGT,
                               const float* __restrict__ t00,
                               const int* __restrict__ idxb,
                               float* __restrict__ s00, float* __restrict__ s10,
                               float* __restrict__ s01) {
  __shared__ float sbuf[4];
  const int b = blockIdx.x, t = threadIdx.x;
  const int ix = idxb[b];
  const float* f = feat + (size_t)b * 2048;
  const float* eg = EG + (size_t)ix * 2048;
  const float* eh = EGT + (size_t)ix * 2048;
  f32x4 fa = *(const f32x4*)(f + t * 8), fb2 = *(const f32x4*)(f + t * 8 + 4);
  f32x4 ga = *(const f32x4*)(eg + t * 8), gb = *(const f32x4*)(eg + t * 8 + 4);
  f32x4 ha = *(const f32x4*)(eh + t * 8), hb = *(const f32x4*)(eh + t * 8 + 4);
  float d01 = 0.f, d10 = 0.f;
#pragma unroll
  for (int u = 0; u < 4; ++u) {
    d01 += fa[u] * ga[u] + fb2[u] * gb[u];
    d10 += fa[u] * ha[u] + fb2[u] * hb[u];
  }
  float r01 = block_sum(d01, sbuf);
  float r10 = block_sum(d10, sbuf);
  if (t == 0) { s01[b] = r01; s10[b] = r10; s00[b] = t00[ix]; }
}

__global__ void scores_final_k(const float* __restrict__ s00p,
                               const float* __restrict__ s10p,
                               const float* __restrict__ s01p,
                               const float* __restrict__ s11p,
                               float* __restrict__ Amat) {
  const int b = blockIdx.x * 256 + threadIdx.x;
  float t00 = s00p[b], t10 = s10p[b], t01 = s01p[b], t11 = s11p[b];
  float m0 = fmaxf(t00, t10), m1 = fmaxf(t01, t11);
  float e00 = expf(t00 - m0), e10 = expf(t10 - m0);
  float e01 = expf(t01 - m1), e11 = expf(t11 - m1);
  float d0 = e00 + e10, d1 = e01 + e11;
  float* Ab = Amat + (size_t)b * 4;
  Ab[0] = e00 / d0; Ab[1] = e10 / d0; Ab[2] = e01 / d1; Ab[3] = e11 / d1;
}

// final out_q gather
__global__ void gather_q_k(const int* __restrict__ idxb,
                           const float* __restrict__ emb,
                           float* __restrict__ outq) {
  const int b = blockIdx.x;
  const int ix = idxb[b];
  const f32x4* src = (const f32x4*)(emb + (size_t)ix * 2048);
  f32x4* dst = (f32x4*)(outq + (size_t)b * 2048);
  dst[threadIdx.x] = src[threadIdx.x];
  dst[threadIdx.x + 256] = src[threadIdx.x + 256];
}

// ---------------------------------------------------------------------------
extern "C" void kernel_launch(void* const* d_in, const int* in_sizes, int n_in,
                              void* d_out, int out_size, void* d_ws,
                              size_t ws_size, hipStream_t stream) {
  const float* feat = (const float*)d_in[0];
  const float* emb = (const float*)d_in[1];
  const float* Kw = (const float*)d_in[2];
  const float* Qw = (const float*)d_in[3];
  const float* Vw = (const float*)d_in[4];
  const float* fuse_w = (const float*)d_in[5];
  const float* fuse_b = (const float*)d_in[6];
  const float* fc_w = (const float*)d_in[7];
  const float* fc_b = (const float*)d_in[8];

  float* out_q = (float*)d_out;                     // 8192*2048 f32 = 64 MiB
  float* out_pred = out_q + (size_t)8192 * 2048;    // 8192*1000 f32
  float* out_idx = out_pred + (size_t)8192 * 1000;  // 8192

  char* ws = (char*)d_ws;
  const size_t MiB = 1024 * 1024;
  float* nx = (float*)(ws + 0);           // 32 KB
  float* nw = (float*)(ws + 32768);       // 4 KB
  float* swp = (float*)(ws + 36864);      // 4 KB
  float* t00 = (float*)(ws + 40960);      // 4 KB
  int* idxb = (int*)(ws + 45056);         // 32 KB
  float* s00 = (float*)(ws + 81920);      // 32 KB
  float* s10 = (float*)(ws + 114688);     // 32 KB
  float* s01 = (float*)(ws + 147456);     // 32 KB
  float* s11 = (float*)(ws + 180224);     // 32 KB
  float* Amat = (float*)(ws + 212992);    // 128 KB
  float* Dmin = (float*)(ws + 360448);    // 256 KB (8192x8)
  int* Darg = (int*)(ws + 622592);        // 256 KB -> ends < 1 MiB
  bf16* G = (bf16*)(ws + 1 * MiB);        // 8 MiB [1,9)   live: big3..s11
  bf16* GT = (bf16*)(ws + 9 * MiB);       // 8 MiB [9,17)  live: transpose..emb4
  bf16* M1 = (bf16*)(ws + 17 * MiB);      // 8 MiB [17,25) live: big3..gemm_h
  bf16* M2 = (bf16*)(ws + 25 * MiB);      // 8 MiB [25,33) live: big3..gemm_h
  // reuse after GT dead (post-emb4):
  bf16* embH = (bf16*)(ws + 9 * MiB);               // 4,096,000 B
  bf16* embL = (bf16*)(ws + 9 * MiB + 4096000);     // 4,096,000 B
  // reuse after M1 dead (post-gemm_h):
  bf16* fc_wB = (bf16*)(ws + 17 * MiB);             // 4,096,000 B

  // out_q region as scratch:
  char* oq = (char*)out_q;
  bf16* KwT = (bf16*)oq;                   // [0,8)  MiB  dead after big3
  bf16* QwT = (bf16*)(oq + 8 * MiB);       // [8,16) MiB  dead after big3
  bf16* VwT = (bf16*)(oq + 16 * MiB);      // [16,24) MiB dead after big3
  bf16* fuse_wB = (bf16*)(oq + 24 * MiB);  // [24,40) MiB dead after big3
  bf16* featH = (bf16*)oq;                 // [0,32) MiB  (post-big3..gemm_h A)
  bf16* featL = (bf16*)(oq + 32 * MiB);    // [32,64) MiB (post-big3..dist)
  bf16* Z0 = (bf16*)(oq + 32 * MiB);       // [32,64) MiB (zgather..gemm_h)
  bf16* Hbuf = Z0;                         // in-place over Z0 (gemm_h..pred)

  // out_pred region: EG|EGT|T1|T2 = 4 x 8,192,000 B (exact fit)
  float* EG = out_pred;
  float* EGT = out_pred + (size_t)2048 * 1000;
  float* T1 = out_pred + (size_t)4096 * 1000;
  float* T2 = out_pred + (size_t)6144 * 1000;

  // --- setup passes ---
  zero_k<<<32, 256, 0, stream>>>(s11);
  transpose3_k<<<dim3(32, 32, 3), 256, 0, stream>>>(Kw, Qw, Vw, KwT, QwT, VwT);
  cvt_k<<<4096, 256, 0, stream>>>(fuse_w, fuse_wB);  // 2048x4096

  // big3 (768 wg): G=Kw^T Qw, M1=W1 Vw, M2=W2 Vw (all-bf16 A)
  gemm4_nt<false, false, 4><<<dim3(16, 16, 3), 256, 0, stream>>>(
      KwT, fuse_wB, fuse_wB + 2048, nullptr, QwT, VwT, VwT, nullptr, G, M1, M2,
      nullptr, 2048, 2048, 4096, 2048, 2048, 1 << 30);

  // GT = G^T (bf16 transpose; replaces the former 2048^3 GEMM)
  transpose_g_k<<<dim3(32, 32), 256, 0, stream>>>(G, GT);

  // emb4 (512 wg): EG=emb@G, EGT=emb@G^T, T1=emb@M1^T, T2=emb@M2^T (A fp32)
  gemm4_nt<true, true, 3><<<dim3(8, 16, 4), 256, 0, stream>>>(
      emb, emb, emb, emb, GT, G, M1, M2, EG, EGT, T1, T2, 2048, 2048, 2048,
      2048, 2048, 999);
  t00_k<<<1000, 256, 0, stream>>>(EG, emb, t00);

  // fused norm+convert passes (KwT/QwT/VwT/fuse_wB and GT now dead)
  featcvt_k<<<8192, 256, 0, stream>>>(feat, featH, featL, nx);
  embcvt_k<<<1000, 256, 0, stream>>>(emb, embH, embL, nw, swp);

  // full-batch distance GEMM (512 wg, hi/lo triple) + argmin
  gemm_nt<EPI_DIST, true, 2><<<dim3(64, 8), 256, 0, stream>>>(
      featH, featL, embH, embL, nullptr, nullptr, nullptr, nullptr, nx, nw,
      swp, Dmin, Darg, 2048, 2048, 2048, 0, 999);
  idx_sel_k<<<32, 256, 0, stream>>>(Dmin, Darg, idxb, out_idx);
  score_gather_k<<<8192, 256, 0, stream>>>(feat, EG, EGT, t00, idxb, s00, s10,
                                           s01);

  // s11 = f^T G f (1024 wg) with fused row-dot epilogue
  gemm_nt<EPI_SCORES, false, 4><<<dim3(64, 16), 256, 0, stream>>>(
      featH, nullptr, G, nullptr, nullptr, nullptr, feat, s11, nullptr,
      nullptr, nullptr, nullptr, nullptr, 2048, 2048, 2048, 0, 2047);
  scores_final_k<<<32, 256, 0, stream>>>(s00, s10, s01, s11, Amat);

  // Z0 = a00*T1[ix] + a01*T2[ix] + fuse_b  (row-contiguous; overwrites featL)
  zgather_k<<<8192, 256, 0, stream>>>(idxb, Amat, T1, T2, fuse_b, Z0);

  // h = relu(a10*featH@M1^T + a11*featH@M2^T + Z0)  (all-bf16; H in-place)
  gemm_h<<<dim3(64, 16), 256, 0, stream>>>(featH, M1, M2, Hbuf, Z0, Amat);

  // fc_w -> bf16 (into ex-M1; M1 dead after gemm_h)
  cvt_k<<<1000, 256, 0, stream>>>(fc_w, fc_wB);

  // pred (512 wg): fp32 out, ragged N=1000 (overwrites EG/EGT/T1/T2 — dead)
  gemm_nt<EPI_BIAS, false, 4><<<dim3(64, 8), 256, 0, stream>>>(
      Hbuf, nullptr, fc_wB, nullptr, out_pred, fc_b, nullptr, nullptr, nullptr,
      nullptr, nullptr, nullptr, nullptr, 2048, 2048, 2048, 1000, 999);

  // final out_q gather (featH/Hbuf scratch dead)
  gather_q_k<<<8192, 256, 0, stream>>>(idxb, emb, out_q);
}